// Round 1
// baseline (6973.130 us; speedup 1.0000x reference)
//
#include <hip/hip_runtime.h>

#define BATCH 512
#define TT 64
#define II 128
#define HH 128
#define EE 127

// ---------------- workspace layout (floats) ----------------
#define SZ_W (128*512)
#define OFF_WihT0e 0
#define OFF_WhhT0e (OFF_WihT0e + SZ_W)
#define OFF_WihT1e (OFF_WhhT0e + SZ_W)
#define OFF_WhhT1e (OFF_WihT1e + SZ_W)
#define OFF_WdhhT0 (OFF_WhhT1e + SZ_W)
#define OFF_WdihT1 (OFF_WdhhT0 + SZ_W)
#define OFF_WdhhT1 (OFF_WdihT1 + SZ_W)
#define OFF_W1hT   (OFF_WdhhT1 + SZ_W)        // 128*64
#define OFF_W1cT   (OFF_W1hT + 128*64)
#define OFF_WdhT   (OFF_W1cT + 128*64)        // 128*128
#define OFF_WdcT   (OFF_WdhT + 128*128)
#define OFF_WdxT   (OFF_WdcT + 128*128)
#define OFF_bsum0e (OFF_WdxT + 128*128)
#define OFF_bsum1e (OFF_bsum0e + 512)
#define OFF_bsum0d (OFF_bsum1e + 512)
#define OFF_bsum1d (OFF_bsum0d + 512)
#define OFF_xprojT (OFF_bsum1d + 512)         // B*64*128  [b][j][e]
#define OFF_hexp   (OFF_xprojT + BATCH*64*128) // B*64*128 [b][t][k]
#define OFF_hprojT (OFF_hexp   + BATCH*64*128) // B*128*64 [b][kk][t]

struct Params {
  const float* input;
  const float *eWih0, *eWhh0, *ebih0, *ebhh0, *eWih1, *eWhh1, *ebih1, *ebhh1;
  const float *dWih0, *dWhh0, *dbih0, *dbhh0, *dWih1, *dWhh1, *dbih1, *dbhh1;
  const float *aW1, *ab1, *aW2, *ab2;
  const float *adW1, *adb1, *adW2, *adb2;
  const float *dinW, *dinb, *projW, *projb;
  float* ws;
  float* out;
};

#define L2E 1.4426950408889634f

__device__ __forceinline__ float exp2f_(float x){ return __builtin_amdgcn_exp2f(x); }
__device__ __forceinline__ float rcp_(float x){ return __builtin_amdgcn_rcpf(x); }
__device__ __forceinline__ float fast_tanh(float x){
  float t = exp2f_(x * 2.8853900817779268f);   // e^{2x}
  return 1.f - 2.f * rcp_(t + 1.f);
}
__device__ __forceinline__ float sigm(float x){
  return rcp_(1.f + exp2f_(-x * L2E));
}
__device__ __forceinline__ float wave_max(float v){
  #pragma unroll
  for (int o = 32; o > 0; o >>= 1) v = fmaxf(v, __shfl_xor(v, o, 64));
  return v;
}
__device__ __forceinline__ float wave_sum(float v){
  #pragma unroll
  for (int o = 32; o > 0; o >>= 1) v += __shfl_xor(v, o, 64);
  return v;
}

// ---------------- prep: transpose weights, fuse biases ----------------
__global__ __launch_bounds__(256) void k_prep(Params p){
  float* ws = p.ws;
  const int gid = blockIdx.x*256 + threadIdx.x;
  const int gsz = gridDim.x*256;
  for (int i = gid; i < SZ_W; i += gsz){
    const int e = i >> 9, j = i & 511;
    ws[OFF_WihT0e + i] = (e < EE) ? p.eWih0[j*EE + e] : 0.f;
    ws[OFF_WhhT0e + i] = p.eWhh0[j*HH + e];
    ws[OFF_WihT1e + i] = p.eWih1[j*HH + e];
    ws[OFF_WhhT1e + i] = p.eWhh1[j*HH + e];
    ws[OFF_WdhhT0 + i] = p.dWhh0[j*HH + e];
    ws[OFF_WdihT1 + i] = p.dWih1[j*HH + e];
    ws[OFF_WdhhT1 + i] = p.dWhh1[j*HH + e];
  }
  for (int i = gid; i < 128*64; i += gsz){
    const int k = i >> 6, jj = i & 63;
    ws[OFF_W1hT + i] = p.aW1[jj*320 + k];
    ws[OFF_W1cT + i] = p.aW1[jj*320 + 128 + k];
  }
  for (int i = gid; i < 128*128; i += gsz){
    const int k = i >> 7, kk = i & 127;
    ws[OFF_WdhT + i] = p.adW1[kk*384 + k];
    ws[OFF_WdcT + i] = p.adW1[kk*384 + 128 + k];
    ws[OFF_WdxT + i] = p.adW1[kk*384 + 256 + k];
  }
  for (int i = gid; i < 512; i += gsz){
    ws[OFF_bsum0e+i] = p.ebih0[i]+p.ebhh0[i];
    ws[OFF_bsum1e+i] = p.ebih1[i]+p.ebhh1[i];
    ws[OFF_bsum0d+i] = p.dbih0[i]+p.dbhh0[i];
    ws[OFF_bsum1d+i] = p.dbih1[i]+p.dbhh1[i];
  }
}

// ---------------- xprojT[b][j][e] = b1[j] + sum_k inp[b,k,1+e]*W1x[j,k] ----
__global__ __launch_bounds__(256) void k_xproj(Params p){
  __shared__ float xin[64][128];   // [k][e]
  __shared__ float w1x[64][64];    // [j][k]
  __shared__ float b1s[64];
  const int b = blockIdx.x, tid = threadIdx.x;
  const float* inb = p.input + b*(TT*II);
  for (int i = tid; i < 64*128; i += 256){
    const int k = i >> 7, e = i & 127;
    xin[k][e] = (e < EE) ? inb[k*II + 1 + e] : 0.f;
  }
  for (int i = tid; i < 64*64; i += 256){
    const int j = i >> 6, k = i & 63;
    w1x[j][k] = p.aW1[j*320 + 256 + k];
  }
  if (tid < 64) b1s[tid] = p.ab1[tid];
  __syncthreads();
  float* outb = p.ws + OFF_xprojT + b*(64*128);
  for (int i = tid; i < 64*128; i += 256){
    const int j = i >> 7, e = i & 127;
    float acc = b1s[j];
    #pragma unroll 8
    for (int k = 0; k < 64; ++k) acc += xin[k][e] * w1x[j][k];
    outb[i] = acc;
  }
}

// ---------------- encoder: 128 blocks x 4 batches, 64 steps ----------------
__global__ __launch_bounds__(256) void k_enc(Params p){
  __shared__ float h0s[4][128], c0s[4][128], h1s[4][128], c1s[4][128];
  __shared__ float xs[4][128];
  __shared__ float g01s[4][64];
  __shared__ float gbuf[4][512];
  __shared__ float w2s[64];
  const int tid = threadIdx.x;
  const int b0 = blockIdx.x * 4;
  float* ws = p.ws;
  for (int i = tid; i < 512; i += 256){
    const int bb = i >> 7, u = i & 127;
    h0s[bb][u]=0.f; c0s[bb][u]=0.f; h1s[bb][u]=0.f; c1s[bb][u]=0.f;
  }
  if (tid < 64) w2s[tid] = p.aW2[tid];
  const float b2 = p.ab2[0];
  const float* W1hT = ws + OFF_W1hT;
  const float* W1cT = ws + OFF_W1cT;
  __syncthreads();

  for (int t = 0; t < TT; ++t){
    // --- E1: g01 = h1@W1h^T + c1@W1c^T  (4x64 outputs, one per thread)
    {
      const int bb = tid >> 6, jj = tid & 63;
      float acc = 0.f;
      #pragma unroll 8
      for (int k = 0; k < 128; ++k)
        acc += h1s[bb][k]*W1hT[k*64+jj] + c1s[bb][k]*W1cT[k*64+jj];
      g01s[bb][jj] = acc;
    }
    __syncthreads();
    // --- E2: logits -> softmax over E -> xs = a * x_t  (wave = batch)
    {
      const int wv = tid >> 6, l = tid & 63;
      const int b = b0 + wv;
      const float* xp = ws + OFF_xprojT + b*8192;
      float acc0 = b2, acc1 = b2;
      #pragma unroll 4
      for (int j = 0; j < 64; ++j){
        const float g = g01s[wv][j];
        const float wj = w2s[j];
        acc0 += wj * fast_tanh(xp[j*128 + l] + g);
        acc1 += wj * fast_tanh(xp[j*128 + 64 + l] + g);
      }
      if (l >= 63) acc1 = -3.0e38f;
      const float m = wave_max(fmaxf(acc0, acc1));
      const float p0 = exp2f_((acc0 - m) * L2E);
      const float p1 = (l < 63) ? exp2f_((acc1 - m) * L2E) : 0.f;
      const float rs = rcp_(wave_sum(p0 + p1));
      const float* xtb = p.input + b*(TT*II) + t*II + 1;
      xs[wv][l]      = p0 * rs * xtb[l];
      xs[wv][64 + l] = (l < 63) ? p1 * rs * xtb[64 + l] : 0.f;
    }
    __syncthreads();
    // --- E3: g0 = xs@WihT0 + h0@WhhT0 + bsum0e
    {
      const int j0 = tid, j1 = tid + 256;
      const float bsA = ws[OFF_bsum0e + j0], bsB = ws[OFF_bsum0e + j1];
      float a00=bsA,a01=bsB,a10=bsA,a11=bsB,a20=bsA,a21=bsB,a30=bsA,a31=bsB;
      const float* Wi = ws + OFF_WihT0e;
      #pragma unroll 8
      for (int e = 0; e < 128; ++e){
        const float w0 = Wi[e*512 + j0], w1 = Wi[e*512 + j1];
        const float x0=xs[0][e], x1=xs[1][e], x2=xs[2][e], x3=xs[3][e];
        a00 += w0*x0; a01 += w1*x0; a10 += w0*x1; a11 += w1*x1;
        a20 += w0*x2; a21 += w1*x2; a30 += w0*x3; a31 += w1*x3;
      }
      const float* Wh = ws + OFF_WhhT0e;
      #pragma unroll 8
      for (int k = 0; k < 128; ++k){
        const float w0 = Wh[k*512 + j0], w1 = Wh[k*512 + j1];
        const float x0=h0s[0][k], x1=h0s[1][k], x2=h0s[2][k], x3=h0s[3][k];
        a00 += w0*x0; a01 += w1*x0; a10 += w0*x1; a11 += w1*x1;
        a20 += w0*x2; a21 += w1*x2; a30 += w0*x3; a31 += w1*x3;
      }
      gbuf[0][j0]=a00; gbuf[0][j1]=a01; gbuf[1][j0]=a10; gbuf[1][j1]=a11;
      gbuf[2][j0]=a20; gbuf[2][j1]=a21; gbuf[3][j0]=a30; gbuf[3][j1]=a31;
    }
    __syncthreads();
    // --- update h0,c0
    for (int i = tid; i < 512; i += 256){
      const int bb = i >> 7, u = i & 127;
      const float gi=gbuf[bb][u], gf=gbuf[bb][128+u], gg=gbuf[bb][256+u], go=gbuf[bb][384+u];
      const float c = sigm(gf)*c0s[bb][u] + sigm(gi)*fast_tanh(gg);
      c0s[bb][u] = c;
      h0s[bb][u] = sigm(go)*fast_tanh(c);
    }
    __syncthreads();
    // --- E4: g1 = h0@WihT1 + h1@WhhT1 + bsum1e
    {
      const int j0 = tid, j1 = tid + 256;
      const float bsA = ws[OFF_bsum1e + j0], bsB = ws[OFF_bsum1e + j1];
      float a00=bsA,a01=bsB,a10=bsA,a11=bsB,a20=bsA,a21=bsB,a30=bsA,a31=bsB;
      const float* Wi = ws + OFF_WihT1e;
      #pragma unroll 8
      for (int k = 0; k < 128; ++k){
        const float w0 = Wi[k*512 + j0], w1 = Wi[k*512 + j1];
        const float x0=h0s[0][k], x1=h0s[1][k], x2=h0s[2][k], x3=h0s[3][k];
        a00 += w0*x0; a01 += w1*x0; a10 += w0*x1; a11 += w1*x1;
        a20 += w0*x2; a21 += w1*x2; a30 += w0*x3; a31 += w1*x3;
      }
      const float* Wh = ws + OFF_WhhT1e;
      #pragma unroll 8
      for (int k = 0; k < 128; ++k){
        const float w0 = Wh[k*512 + j0], w1 = Wh[k*512 + j1];
        const float x0=h1s[0][k], x1=h1s[1][k], x2=h1s[2][k], x3=h1s[3][k];
        a00 += w0*x0; a01 += w1*x0; a10 += w0*x1; a11 += w1*x1;
        a20 += w0*x2; a21 += w1*x2; a30 += w0*x3; a31 += w1*x3;
      }
      gbuf[0][j0]=a00; gbuf[0][j1]=a01; gbuf[1][j0]=a10; gbuf[1][j1]=a11;
      gbuf[2][j0]=a20; gbuf[2][j1]=a21; gbuf[3][j0]=a30; gbuf[3][j1]=a31;
    }
    __syncthreads();
    // --- update h1,c1, write h_exp
    for (int i = tid; i < 512; i += 256){
      const int bb = i >> 7, u = i & 127;
      const float gi=gbuf[bb][u], gf=gbuf[bb][128+u], gg=gbuf[bb][256+u], go=gbuf[bb][384+u];
      const float c = sigm(gf)*c1s[bb][u] + sigm(gi)*fast_tanh(gg);
      c1s[bb][u] = c;
      const float h = sigm(go)*fast_tanh(c);
      h1s[bb][u] = h;
      ws[OFF_hexp + (size_t)(b0+bb)*8192 + t*128 + u] = h;
    }
    __syncthreads();
  }
}

// ---------------- hprojT[b][kk][t] = adb1[kk] + sum_k hexp[b][t][k]*WdxT[k][kk]
__global__ __launch_bounds__(256) void k_hproj(Params p){
  __shared__ float hx[64][129];   // [t][k] padded
  __shared__ float bs[128];
  const int b = blockIdx.x, tid = threadIdx.x;
  const float* hb = p.ws + OFF_hexp + (size_t)b*8192;
  for (int i = tid; i < 64*128; i += 256){
    const int t = i >> 7, k = i & 127;
    hx[t][k] = hb[i];
  }
  if (tid < 128) bs[tid] = p.adb1[tid];
  __syncthreads();
  float* outb = p.ws + OFF_hprojT + (size_t)b*8192;
  for (int i = tid; i < 128*64; i += 256){
    const int kk = i >> 6, t = i & 63;
    float acc = bs[kk];
    const float* w = p.ws + OFF_WdxT + kk;
    #pragma unroll 8
    for (int k = 0; k < 128; ++k) acc += hx[t][k] * w[k*128];
    outb[i] = acc;
  }
}

// ---------------- decoder: 128 blocks x 4 batches, 64 steps + final proj ----
__global__ __launch_bounds__(256) void k_dec(Params p){
  __shared__ float h0s[4][128], c0s[4][128], h1s[4][128], c1s[4][128];
  __shared__ float parts[4][128];
  __shared__ float g01d[4][128];
  __shared__ float abuf[4][64];
  __shared__ float gbuf[4][512];
  __shared__ float wd2s[128];
  __shared__ float dins[4];
  const int tid = threadIdx.x;
  const int b0 = blockIdx.x * 4;
  float* ws = p.ws;
  for (int i = tid; i < 512; i += 256){
    const int bb = i >> 7, u = i & 127;
    h0s[bb][u]=0.f; c0s[bb][u]=0.f; h1s[bb][u]=0.f; c1s[bb][u]=0.f;
  }
  if (tid < 128) wd2s[tid] = p.adW2[tid];
  const float bd2 = p.adb2[0];
  const float* WdhT = ws + OFF_WdhT;
  const float* WdcT = ws + OFF_WdcT;
  __syncthreads();

  for (int t = 0; t < TT; ++t){
    // --- D1: g01d = h1@WdhT + c1@WdcT (4x128)
    for (int item = tid; item < 512; item += 256){
      const int bb = item >> 7, kk = item & 127;
      float acc = 0.f;
      #pragma unroll 8
      for (int k = 0; k < 128; ++k)
        acc += h1s[bb][k]*WdhT[k*128+kk] + c1s[bb][k]*WdcT[k*128+kk];
      g01d[bb][kk] = acc;
    }
    __syncthreads();
    // --- D2: logits over T, softmax (wave = batch, lane = t')
    {
      const int wv = tid >> 6, l = tid & 63;
      const int b = b0 + wv;
      const float* hp = ws + OFF_hprojT + (size_t)b*8192;
      float acc = bd2;
      #pragma unroll 4
      for (int kk = 0; kk < 128; ++kk)
        acc += wd2s[kk] * fast_tanh(hp[kk*64 + l] + g01d[wv][kk]);
      const float m = wave_max(acc);
      const float pe = exp2f_((acc - m) * L2E);
      abuf[wv][l] = pe * rcp_(wave_sum(pe));
    }
    __syncthreads();
    // --- D2b: partial[bb][h] = sum_t' a * hexp
    for (int item = tid; item < 512; item += 256){
      const int bb = item >> 7, h = item & 127;
      const float* he = ws + OFF_hexp + (size_t)(b0+bb)*8192 + h;
      float acc = 0.f;
      #pragma unroll 8
      for (int tt2 = 0; tt2 < 64; ++tt2) acc += abuf[bb][tt2] * he[tt2*128];
      parts[bb][h] = acc;
    }
    __syncthreads();
    // --- D2c: din per batch
    {
      const int wv = tid >> 6, l = tid & 63;
      float v = parts[wv][l]*p.dinW[l] + parts[wv][64+l]*p.dinW[64+l];
      v = wave_sum(v);
      if (l == 0){
        const float xd = p.input[(size_t)(b0+wv)*(TT*II) + t*II];
        dins[wv] = v + xd*p.dinW[128] + p.dinb[0];
      }
    }
    __syncthreads();
    // --- D3: g0 = din*dWih0 + h0@WdhhT0 + bsum0d (K=128)
    {
      const int j0 = tid, j1 = tid + 256;
      const float w00 = p.dWih0[j0], w01 = p.dWih0[j1];
      const float bsA = ws[OFF_bsum0d + j0], bsB = ws[OFF_bsum0d + j1];
      float a00=bsA+dins[0]*w00, a01=bsB+dins[0]*w01;
      float a10=bsA+dins[1]*w00, a11=bsB+dins[1]*w01;
      float a20=bsA+dins[2]*w00, a21=bsB+dins[2]*w01;
      float a30=bsA+dins[3]*w00, a31=bsB+dins[3]*w01;
      const float* Wh = ws + OFF_WdhhT0;
      #pragma unroll 8
      for (int k = 0; k < 128; ++k){
        const float w0 = Wh[k*512 + j0], w1 = Wh[k*512 + j1];
        const float x0=h0s[0][k], x1=h0s[1][k], x2=h0s[2][k], x3=h0s[3][k];
        a00 += w0*x0; a01 += w1*x0; a10 += w0*x1; a11 += w1*x1;
        a20 += w0*x2; a21 += w1*x2; a30 += w0*x3; a31 += w1*x3;
      }
      gbuf[0][j0]=a00; gbuf[0][j1]=a01; gbuf[1][j0]=a10; gbuf[1][j1]=a11;
      gbuf[2][j0]=a20; gbuf[2][j1]=a21; gbuf[3][j0]=a30; gbuf[3][j1]=a31;
    }
    __syncthreads();
    for (int i = tid; i < 512; i += 256){
      const int bb = i >> 7, u = i & 127;
      const float gi=gbuf[bb][u], gf=gbuf[bb][128+u], gg=gbuf[bb][256+u], go=gbuf[bb][384+u];
      const float c = sigm(gf)*c0s[bb][u] + sigm(gi)*fast_tanh(gg);
      c0s[bb][u] = c;
      h0s[bb][u] = sigm(go)*fast_tanh(c);
    }
    __syncthreads();
    // --- D4: g1 = h0@WdihT1 + h1@WdhhT1 + bsum1d (K=256)
    {
      const int j0 = tid, j1 = tid + 256;
      const float bsA = ws[OFF_bsum1d + j0], bsB = ws[OFF_bsum1d + j1];
      float a00=bsA,a01=bsB,a10=bsA,a11=bsB,a20=bsA,a21=bsB,a30=bsA,a31=bsB;
      const float* Wi = ws + OFF_WdihT1;
      #pragma unroll 8
      for (int k = 0; k < 128; ++k){
        const float w0 = Wi[k*512 + j0], w1 = Wi[k*512 + j1];
        const float x0=h0s[0][k], x1=h0s[1][k], x2=h0s[2][k], x3=h0s[3][k];
        a00 += w0*x0; a01 += w1*x0; a10 += w0*x1; a11 += w1*x1;
        a20 += w0*x2; a21 += w1*x2; a30 += w0*x3; a31 += w1*x3;
      }
      const float* Wh = ws + OFF_WdhhT1;
      #pragma unroll 8
      for (int k = 0; k < 128; ++k){
        const float w0 = Wh[k*512 + j0], w1 = Wh[k*512 + j1];
        const float x0=h1s[0][k], x1=h1s[1][k], x2=h1s[2][k], x3=h1s[3][k];
        a00 += w0*x0; a01 += w1*x0; a10 += w0*x1; a11 += w1*x1;
        a20 += w0*x2; a21 += w1*x2; a30 += w0*x3; a31 += w1*x3;
      }
      gbuf[0][j0]=a00; gbuf[0][j1]=a01; gbuf[1][j0]=a10; gbuf[1][j1]=a11;
      gbuf[2][j0]=a20; gbuf[2][j1]=a21; gbuf[3][j0]=a30; gbuf[3][j1]=a31;
    }
    __syncthreads();
    for (int i = tid; i < 512; i += 256){
      const int bb = i >> 7, u = i & 127;
      const float gi=gbuf[bb][u], gf=gbuf[bb][128+u], gg=gbuf[bb][256+u], go=gbuf[bb][384+u];
      const float c = sigm(gf)*c1s[bb][u] + sigm(gi)*fast_tanh(gg);
      c1s[bb][u] = c;
      h1s[bb][u] = sigm(go)*fast_tanh(c);
    }
    __syncthreads();
  }
  // --- final: out[b] = [h1, partial] @ proj_W^T + proj_b
  {
    const int wv = tid >> 6, l = tid & 63;
    float v = h1s[wv][l]*p.projW[l] + h1s[wv][64+l]*p.projW[64+l]
            + parts[wv][l]*p.projW[128+l] + parts[wv][64+l]*p.projW[192+l];
    v = wave_sum(v);
    if (l == 0) p.out[b0 + wv] = v + p.projb[0];
  }
}

extern "C" void kernel_launch(void* const* d_in, const int* in_sizes, int n_in,
                              void* d_out, int out_size, void* d_ws, size_t ws_size,
                              hipStream_t stream){
  Params p;
  p.input = (const float*)d_in[0];
  p.eWih0=(const float*)d_in[1];  p.eWhh0=(const float*)d_in[2];
  p.ebih0=(const float*)d_in[3];  p.ebhh0=(const float*)d_in[4];
  p.eWih1=(const float*)d_in[5];  p.eWhh1=(const float*)d_in[6];
  p.ebih1=(const float*)d_in[7];  p.ebhh1=(const float*)d_in[8];
  p.dWih0=(const float*)d_in[9];  p.dWhh0=(const float*)d_in[10];
  p.dbih0=(const float*)d_in[11]; p.dbhh0=(const float*)d_in[12];
  p.dWih1=(const float*)d_in[13]; p.dWhh1=(const float*)d_in[14];
  p.dbih1=(const float*)d_in[15]; p.dbhh1=(const float*)d_in[16];
  p.aW1=(const float*)d_in[17];   p.ab1=(const float*)d_in[18];
  p.aW2=(const float*)d_in[19];   p.ab2=(const float*)d_in[20];
  p.adW1=(const float*)d_in[21];  p.adb1=(const float*)d_in[22];
  p.adW2=(const float*)d_in[23];  p.adb2=(const float*)d_in[24];
  p.dinW=(const float*)d_in[25];  p.dinb=(const float*)d_in[26];
  p.projW=(const float*)d_in[27]; p.projb=(const float*)d_in[28];
  p.ws = (float*)d_ws;
  p.out = (float*)d_out;

  hipLaunchKernelGGL(k_prep,  dim3(256), dim3(256), 0, stream, p);
  hipLaunchKernelGGL(k_xproj, dim3(BATCH), dim3(256), 0, stream, p);
  hipLaunchKernelGGL(k_enc,   dim3(128), dim3(256), 0, stream, p);
  hipLaunchKernelGGL(k_hproj, dim3(BATCH), dim3(256), 0, stream, p);
  hipLaunchKernelGGL(k_dec,   dim3(128), dim3(256), 0, stream, p);
}

// Round 2
// 4665.678 us; speedup vs baseline: 1.4946x; 1.4946x over previous
//
#include <hip/hip_runtime.h>

#define BATCH 512
#define TT 64
#define II 128

// ---------------- workspace layout (floats) ----------------
#define OFF_Wr_e0 0                         // [512][256] rows: [Wih0(x,pad)|Whh0(h0)]
#define OFF_Wr_e1 (OFF_Wr_e0 + 512*256)     // [512][256] rows: [Wih1(h0)|Whh1(h1)]
#define OFF_Wr_d1 (OFF_Wr_e1 + 512*256)     // [512][256] rows: [dWih1(h0)|dWhh1(h1)]
#define OFF_bs0e  (OFF_Wr_d1 + 512*256)
#define OFF_bs1e  (OFF_bs0e + 512)
#define OFF_bs0d  (OFF_bs1e + 512)
#define OFF_bs1d  (OFF_bs0d + 512)
#define OFF_xprojT (OFF_bs1d + 512)          // [B][64j][128e]
#define OFF_hexp   (OFF_xprojT + BATCH*8192) // [B][64t][128k]
#define OFF_hprojT (OFF_hexp + BATCH*8192)   // [B][128kk][64t]

struct Params {
  const float* input;
  const float *eWih0, *eWhh0, *ebih0, *ebhh0, *eWih1, *eWhh1, *ebih1, *ebhh1;
  const float *dWih0, *dWhh0, *dbih0, *dbhh0, *dWih1, *dWhh1, *dbih1, *dbhh1;
  const float *aW1, *ab1, *aW2, *ab2;
  const float *adW1, *adb1, *adW2, *adb2;
  const float *dinW, *dinb, *projW, *projb;
  float* ws;
  float* out;
};

#define L2E 1.4426950408889634f

__device__ __forceinline__ float exp2f_(float x){ return __builtin_amdgcn_exp2f(x); }
__device__ __forceinline__ float rcp_(float x){ return __builtin_amdgcn_rcpf(x); }
__device__ __forceinline__ float fast_tanh(float x){
  float t = exp2f_(x * 2.8853900817779268f);   // e^{2x}
  return 1.f - 2.f * rcp_(t + 1.f);
}
__device__ __forceinline__ float sigm(float x){
  return rcp_(1.f + exp2f_(-x * L2E));
}
__device__ __forceinline__ float wave_max(float v){
  #pragma unroll
  for (int o = 32; o > 0; o >>= 1) v = fmaxf(v, __shfl_xor(v, o, 64));
  return v;
}
__device__ __forceinline__ float wave_sum(float v){
  #pragma unroll
  for (int o = 32; o > 0; o >>= 1) v += __shfl_xor(v, o, 64);
  return v;
}

// ---------------- prep: build row-major fused weight rows + bias sums -------
__global__ __launch_bounds__(256) void k_prep(Params p){
  float* ws = p.ws;
  const int gid = blockIdx.x*256 + threadIdx.x;
  const int gsz = gridDim.x*256;
  for (int i = gid; i < 512*256; i += gsz){
    const int j = i >> 8, k = i & 255;
    ws[OFF_Wr_e0 + i] = (k < 128) ? ((k < 127) ? p.eWih0[j*127 + k] : 0.f)
                                  : p.eWhh0[j*128 + (k-128)];
    ws[OFF_Wr_e1 + i] = (k < 128) ? p.eWih1[j*128 + k] : p.eWhh1[j*128 + (k-128)];
    ws[OFF_Wr_d1 + i] = (k < 128) ? p.dWih1[j*128 + k] : p.dWhh1[j*128 + (k-128)];
  }
  for (int i = gid; i < 512; i += gsz){
    ws[OFF_bs0e+i] = p.ebih0[i]+p.ebhh0[i];
    ws[OFF_bs1e+i] = p.ebih1[i]+p.ebhh1[i];
    ws[OFF_bs0d+i] = p.dbih0[i]+p.dbhh0[i];
    ws[OFF_bs1d+i] = p.dbih1[i]+p.dbhh1[i];
  }
}

// ---------------- xprojT[b][j][e] = ab1[j] + sum_k inp[b,k,1+e]*W1x[j,k] ----
__global__ __launch_bounds__(256) void k_xproj(Params p){
  __shared__ float xin[64][128];   // [k][e]
  __shared__ float w1x[64][64];    // [j][k]
  __shared__ float b1s[64];
  const int b = blockIdx.x, tid = threadIdx.x;
  const float* inb = p.input + (size_t)b*(TT*II);
  for (int i = tid; i < 64*128; i += 256){
    const int k = i >> 7, e = i & 127;
    xin[k][e] = (e < 127) ? inb[k*II + 1 + e] : 0.f;
  }
  for (int i = tid; i < 64*64; i += 256){
    const int j = i >> 6, k = i & 63;
    w1x[j][k] = p.aW1[j*320 + 256 + k];
  }
  if (tid < 64) b1s[tid] = p.ab1[tid];
  __syncthreads();
  float* outb = p.ws + OFF_xprojT + (size_t)b*8192;
  for (int i = tid; i < 64*128; i += 256){
    const int j = i >> 7, e = i & 127;
    float acc = b1s[j];
    #pragma unroll 8
    for (int k = 0; k < 64; ++k) acc += xin[k][e] * w1x[j][k];
    outb[i] = acc;
  }
}

// ---------------- encoder: 128 blocks x 4 batches, 512 threads -------------
__global__ __launch_bounds__(512) void k_enc(Params p){
  __shared__ float S[4][512];      // per batch: [x(128)|h0(128)|h1(128)|c1(128)]
  __shared__ float c0s[4][128];
  __shared__ float gp0[4][512], gp1[4][512];
  __shared__ float gpE1[8*256];    // [eighth][bb*64+jj]
  __shared__ float g01s[256];      // [bb*64+jj]
  __shared__ float w2s[64];
  __shared__ float pmaxs[4][2], psums[4][2];
  __shared__ float bs0[512], bs1[512];
  const int tid = threadIdx.x;
  const int b0 = blockIdx.x * 4;
  float* ws = p.ws;
  for (int i = tid; i < 2048; i += 512) (&S[0][0])[i] = 0.f;
  (&c0s[0][0])[tid] = 0.f;
  bs0[tid] = ws[OFF_bs0e + tid];
  bs1[tid] = ws[OFF_bs1e + tid];
  if (tid < 64) w2s[tid] = p.aW2[tid];
  const float b2 = p.ab2[0];
  __syncthreads();
  const int wv = tid >> 6, l = tid & 63;

  for (int t = 0; t < TT; ++t){
    // --- E1: partial g01[bb][jj] = sum_k S[bb][256+k]*aW1[jj][k], K-chunked
    {
      const int eighth = wv, jj = l;
      const int koff = eighth * 32;
      const float* wr = p.aW1 + jj*320 + koff;
      float a0=0.f,a1=0.f,a2=0.f,a3=0.f;
      #pragma unroll
      for (int g = 0; g < 8; ++g){
        const float4 w = *reinterpret_cast<const float4*>(wr + g*4);
        const int k = 256 + koff + g*4;
        const float4 x0 = *reinterpret_cast<const float4*>(&S[0][k]);
        const float4 x1 = *reinterpret_cast<const float4*>(&S[1][k]);
        const float4 x2 = *reinterpret_cast<const float4*>(&S[2][k]);
        const float4 x3 = *reinterpret_cast<const float4*>(&S[3][k]);
        a0 += w.x*x0.x + w.y*x0.y + w.z*x0.z + w.w*x0.w;
        a1 += w.x*x1.x + w.y*x1.y + w.z*x1.z + w.w*x1.w;
        a2 += w.x*x2.x + w.y*x2.y + w.z*x2.z + w.w*x2.w;
        a3 += w.x*x3.x + w.y*x3.y + w.z*x3.z + w.w*x3.w;
      }
      gpE1[eighth*256 + 0*64 + jj] = a0;
      gpE1[eighth*256 + 1*64 + jj] = a1;
      gpE1[eighth*256 + 2*64 + jj] = a2;
      gpE1[eighth*256 + 3*64 + jj] = a3;
    }
    __syncthreads();
    if (tid < 256){
      float s = 0.f;
      #pragma unroll
      for (int q = 0; q < 8; ++q) s += gpE1[q*256 + tid];
      g01s[tid] = s;
    }
    __syncthreads();
    // --- E2a: logits, per-wave softmax partials (wave = (bb, e-half))
    float acc_logit;
    {
      const int bb = wv >> 1, hf = wv & 1;
      const int e = hf*64 + l;
      const int b = b0 + bb;
      const float* xp = ws + OFF_xprojT + (size_t)b*8192 + e;
      const float* g01 = g01s + bb*64;
      float acc = b2;
      #pragma unroll 8
      for (int j = 0; j < 64; ++j)
        acc += w2s[j] * fast_tanh(xp[j*128] + g01[j]);
      if (e >= 127) acc = -3.0e38f;
      const float m = wave_max(acc);
      const float pe = exp2f_((acc - m)*L2E);
      const float sm = wave_sum(pe);
      if (l == 0){ pmaxs[bb][hf] = m; psums[bb][hf] = sm; }
      acc_logit = acc;
    }
    __syncthreads();
    // --- E2b: finish softmax, S.x = a * x_t
    {
      const int bb = wv >> 1, hf = wv & 1;
      const int e = hf*64 + l;
      const int b = b0 + bb;
      const float m0 = pmaxs[bb][0], m1 = pmaxs[bb][1];
      const float gm = fmaxf(m0, m1);
      const float tot = psums[bb][0]*exp2f_((m0-gm)*L2E)
                      + psums[bb][1]*exp2f_((m1-gm)*L2E);
      const float a = exp2f_((acc_logit - gm)*L2E) * rcp_(tot);
      float xv = 0.f;
      if (e < 127) xv = p.input[(size_t)b*8192 + t*128 + 1 + e] * a;
      S[bb][e] = xv;
    }
    __syncthreads();
    // --- E3: gate GEMM layer0: operand S[0..255] (x,h0), rows Wr_e0
    {
      const int half = tid >> 8, u = tid & 255;
      const int j0 = u*2;
      const float* r0 = ws + OFF_Wr_e0 + j0*256 + half*128;
      const float* r1 = r0 + 256;
      float a0[4] = {0,0,0,0}, a1[4] = {0,0,0,0};
      #pragma unroll 4
      for (int kg = 0; kg < 32; ++kg){
        const float4 w0 = *reinterpret_cast<const float4*>(r0 + kg*4);
        const float4 w1 = *reinterpret_cast<const float4*>(r1 + kg*4);
        const int k = half*128 + kg*4;
        #pragma unroll
        for (int bb = 0; bb < 4; ++bb){
          const float4 xv = *reinterpret_cast<const float4*>(&S[bb][k]);
          a0[bb] += w0.x*xv.x + w0.y*xv.y + w0.z*xv.z + w0.w*xv.w;
          a1[bb] += w1.x*xv.x + w1.y*xv.y + w1.z*xv.z + w1.w*xv.w;
        }
      }
      float* gp = half ? &gp1[0][0] : &gp0[0][0];
      #pragma unroll
      for (int bb = 0; bb < 4; ++bb){
        gp[bb*512 + j0]   = a0[bb];
        gp[bb*512 + j0+1] = a1[bb];
      }
    }
    __syncthreads();
    // --- A0: update h0, c0
    {
      const int bb = tid >> 7, u = tid & 127;
      const float gi = gp0[bb][u]     + gp1[bb][u]     + bs0[u];
      const float gf = gp0[bb][128+u] + gp1[bb][128+u] + bs0[128+u];
      const float gg = gp0[bb][256+u] + gp1[bb][256+u] + bs0[256+u];
      const float go = gp0[bb][384+u] + gp1[bb][384+u] + bs0[384+u];
      const float c = sigm(gf)*c0s[bb][u] + sigm(gi)*fast_tanh(gg);
      c0s[bb][u] = c;
      S[bb][128+u] = sigm(go)*fast_tanh(c);
    }
    __syncthreads();
    // --- E4: gate GEMM layer1: operand S[128..383] (h0,h1), rows Wr_e1
    {
      const int half = tid >> 8, u = tid & 255;
      const int j0 = u*2;
      const float* r0 = ws + OFF_Wr_e1 + j0*256 + half*128;
      const float* r1 = r0 + 256;
      float a0[4] = {0,0,0,0}, a1[4] = {0,0,0,0};
      #pragma unroll 4
      for (int kg = 0; kg < 32; ++kg){
        const float4 w0 = *reinterpret_cast<const float4*>(r0 + kg*4);
        const float4 w1 = *reinterpret_cast<const float4*>(r1 + kg*4);
        const int k = 128 + half*128 + kg*4;
        #pragma unroll
        for (int bb = 0; bb < 4; ++bb){
          const float4 xv = *reinterpret_cast<const float4*>(&S[bb][k]);
          a0[bb] += w0.x*xv.x + w0.y*xv.y + w0.z*xv.z + w0.w*xv.w;
          a1[bb] += w1.x*xv.x + w1.y*xv.y + w1.z*xv.z + w1.w*xv.w;
        }
      }
      float* gp = half ? &gp1[0][0] : &gp0[0][0];
      #pragma unroll
      for (int bb = 0; bb < 4; ++bb){
        gp[bb*512 + j0]   = a0[bb];
        gp[bb*512 + j0+1] = a1[bb];
      }
    }
    __syncthreads();
    // --- A1: update h1, c1, write h_exp
    {
      const int bb = tid >> 7, u = tid & 127;
      const float gi = gp0[bb][u]     + gp1[bb][u]     + bs1[u];
      const float gf = gp0[bb][128+u] + gp1[bb][128+u] + bs1[128+u];
      const float gg = gp0[bb][256+u] + gp1[bb][256+u] + bs1[256+u];
      const float go = gp0[bb][384+u] + gp1[bb][384+u] + bs1[384+u];
      const float c = sigm(gf)*S[bb][384+u] + sigm(gi)*fast_tanh(gg);
      S[bb][384+u] = c;
      const float h = sigm(go)*fast_tanh(c);
      S[bb][256+u] = h;
      ws[OFF_hexp + (size_t)(b0+bb)*8192 + t*128 + u] = h;
    }
    __syncthreads();
  }
}

// ---------------- hprojT[b][kk][t] = adb1[kk] + sum_k hexp[b][t][k]*adW1[kk][256+k]
__global__ __launch_bounds__(256) void k_hproj(Params p){
  __shared__ float hx[64][129];   // [t][k] padded
  __shared__ float bs[128];
  const int b = blockIdx.x, tid = threadIdx.x;
  const float* hb = p.ws + OFF_hexp + (size_t)b*8192;
  for (int i = tid; i < 64*128; i += 256){
    hx[i>>7][i&127] = hb[i];
  }
  if (tid < 128) bs[tid] = p.adb1[tid];
  __syncthreads();
  float* outb = p.ws + OFF_hprojT + (size_t)b*8192;
  for (int i = tid; i < 128*64; i += 256){
    const int kk = i >> 6, t2 = i & 63;
    const float* w = p.adW1 + kk*384 + 256;
    float acc = bs[kk];
    #pragma unroll 8
    for (int k = 0; k < 128; ++k) acc += hx[t2][k] * w[k];
    outb[i] = acc;
  }
}

// ---------------- decoder: 128 blocks x 4 batches, 512 threads -------------
__global__ __launch_bounds__(512) void k_dec(Params p){
  __shared__ float S[4][512];      // [unused|h0|h1|c1]
  __shared__ float c0s[4][128];
  __shared__ float gp0[4][512], gp1[4][512];
  __shared__ float gpD1[16*128];   // [quarter*4+bb][kk]
  __shared__ float g01d[4][128];
  __shared__ float dlog[4][2][64];
  __shared__ float abuf[4][64];
  __shared__ float parts[4][128];
  __shared__ float dins[4];
  __shared__ float wd2s[128];
  __shared__ float dW0s[512];
  __shared__ float bs0[512], bs1[512];
  __shared__ float dinWs[132];
  __shared__ float projWs[256];
  const int tid = threadIdx.x;
  const int b0 = blockIdx.x * 4;
  float* ws = p.ws;
  for (int i = tid; i < 2048; i += 512) (&S[0][0])[i] = 0.f;
  (&c0s[0][0])[tid] = 0.f;
  bs0[tid] = ws[OFF_bs0d + tid];
  bs1[tid] = ws[OFF_bs1d + tid];
  dW0s[tid] = p.dWih0[tid];
  if (tid < 128) wd2s[tid] = p.adW2[tid];
  if (tid < 256) projWs[tid] = p.projW[tid];
  if (tid < 129) dinWs[tid] = p.dinW[tid];
  if (tid == 129) dinWs[129] = p.dinb[0];
  const float bd2 = p.adb2[0];
  const float pb = p.projb[0];
  __syncthreads();
  const int wv = tid >> 6, l = tid & 63;

  for (int t = 0; t < TT; ++t){
    // --- D1: partial g01d[bb][kk] over K-quarters; rows = adW1[kk][0..255]
    {
      const int quarter = tid >> 7, kk = tid & 127;
      const int koff = quarter * 64;
      const float* wr = p.adW1 + kk*384 + koff;
      float a0=0.f,a1=0.f,a2=0.f,a3=0.f;
      #pragma unroll 4
      for (int kg = 0; kg < 16; ++kg){
        const float4 w = *reinterpret_cast<const float4*>(wr + kg*4);
        const int k = 256 + koff + kg*4;
        const float4 x0 = *reinterpret_cast<const float4*>(&S[0][k]);
        const float4 x1 = *reinterpret_cast<const float4*>(&S[1][k]);
        const float4 x2 = *reinterpret_cast<const float4*>(&S[2][k]);
        const float4 x3 = *reinterpret_cast<const float4*>(&S[3][k]);
        a0 += w.x*x0.x + w.y*x0.y + w.z*x0.z + w.w*x0.w;
        a1 += w.x*x1.x + w.y*x1.y + w.z*x1.z + w.w*x1.w;
        a2 += w.x*x2.x + w.y*x2.y + w.z*x2.z + w.w*x2.w;
        a3 += w.x*x3.x + w.y*x3.y + w.z*x3.z + w.w*x3.w;
      }
      gpD1[(quarter*4+0)*128+kk] = a0;
      gpD1[(quarter*4+1)*128+kk] = a1;
      gpD1[(quarter*4+2)*128+kk] = a2;
      gpD1[(quarter*4+3)*128+kk] = a3;
    }
    __syncthreads();
    {
      const int bb = tid >> 7, kk = tid & 127;
      float s = 0.f;
      #pragma unroll
      for (int q = 0; q < 4; ++q) s += gpD1[(q*4+bb)*128+kk];
      g01d[bb][kk] = s;
    }
    __syncthreads();
    // --- D2a: logit partials (wave = (bb, kk-half)); lane = t'
    {
      const int bb = wv >> 1, kh = wv & 1;
      const int b = b0 + bb;
      const float* hp = ws + OFF_hprojT + (size_t)b*8192 + l;
      float acc = 0.f;
      #pragma unroll 8
      for (int kk2 = 0; kk2 < 64; ++kk2){
        const int kk = kh*64 + kk2;
        acc += wd2s[kk] * fast_tanh(hp[kk*64] + g01d[bb][kk]);
      }
      dlog[bb][kh][l] = acc;
    }
    __syncthreads();
    // --- D2b: softmax over t' (dup waves write identical values)
    {
      const int bb = wv & 3;
      float acc = dlog[bb][0][l] + dlog[bb][1][l] + bd2;
      const float m = wave_max(acc);
      const float pe = exp2f_((acc - m)*L2E);
      const float sm = wave_sum(pe);
      abuf[bb][l] = pe * rcp_(sm);
    }
    __syncthreads();
    // --- D2c: parts[bb][h] = sum_t' a[t'] * hexp[b][t'][h]
    {
      const int bb = tid >> 7, h = tid & 127;
      const float* he = ws + OFF_hexp + (size_t)(b0+bb)*8192 + h;
      float acc = 0.f;
      #pragma unroll 4
      for (int kg = 0; kg < 16; ++kg){
        const float4 av = *reinterpret_cast<const float4*>(&abuf[bb][kg*4]);
        acc += av.x*he[(kg*4+0)*128] + av.y*he[(kg*4+1)*128]
             + av.z*he[(kg*4+2)*128] + av.w*he[(kg*4+3)*128];
      }
      parts[bb][h] = acc;
    }
    __syncthreads();
    // --- D2d: din
    {
      const int bb = wv & 3;
      float v = parts[bb][l]*dinWs[l] + parts[bb][64+l]*dinWs[64+l];
      v = wave_sum(v);
      if (l == 0){
        const float xd = p.input[(size_t)(b0+bb)*8192 + t*128];
        dins[bb] = v + xd*dinWs[128] + dinWs[129];
      }
    }
    __syncthreads();
    // --- D3: layer0 gate GEMM (K=128, h0 only), rows = dWhh0
    {
      const int half = tid >> 8, u = tid & 255;
      const int j0 = u*2;
      const float* r0 = p.dWhh0 + j0*128 + half*64;
      const float* r1 = r0 + 128;
      float a0[4] = {0,0,0,0}, a1[4] = {0,0,0,0};
      #pragma unroll 4
      for (int kg = 0; kg < 16; ++kg){
        const float4 w0 = *reinterpret_cast<const float4*>(r0 + kg*4);
        const float4 w1 = *reinterpret_cast<const float4*>(r1 + kg*4);
        const int k = 128 + half*64 + kg*4;
        #pragma unroll
        for (int bb = 0; bb < 4; ++bb){
          const float4 xv = *reinterpret_cast<const float4*>(&S[bb][k]);
          a0[bb] += w0.x*xv.x + w0.y*xv.y + w0.z*xv.z + w0.w*xv.w;
          a1[bb] += w1.x*xv.x + w1.y*xv.y + w1.z*xv.z + w1.w*xv.w;
        }
      }
      float* gp = half ? &gp1[0][0] : &gp0[0][0];
      #pragma unroll
      for (int bb = 0; bb < 4; ++bb){
        gp[bb*512 + j0]   = a0[bb];
        gp[bb*512 + j0+1] = a1[bb];
      }
    }
    __syncthreads();
    // --- A2: update h0, c0 (adds din rank-1 term)
    {
      const int bb = tid >> 7, u = tid & 127;
      const float dn = dins[bb];
      const float gi = gp0[bb][u]     + gp1[bb][u]     + bs0[u]     + dn*dW0s[u];
      const float gf = gp0[bb][128+u] + gp1[bb][128+u] + bs0[128+u] + dn*dW0s[128+u];
      const float gg = gp0[bb][256+u] + gp1[bb][256+u] + bs0[256+u] + dn*dW0s[256+u];
      const float go = gp0[bb][384+u] + gp1[bb][384+u] + bs0[384+u] + dn*dW0s[384+u];
      const float c = sigm(gf)*c0s[bb][u] + sigm(gi)*fast_tanh(gg);
      c0s[bb][u] = c;
      S[bb][128+u] = sigm(go)*fast_tanh(c);
    }
    __syncthreads();
    // --- D4: layer1 gate GEMM: operand S[128..383] (h0,h1), rows Wr_d1
    {
      const int half = tid >> 8, u = tid & 255;
      const int j0 = u*2;
      const float* r0 = ws + OFF_Wr_d1 + j0*256 + half*128;
      const float* r1 = r0 + 256;
      float a0[4] = {0,0,0,0}, a1[4] = {0,0,0,0};
      #pragma unroll 4
      for (int kg = 0; kg < 32; ++kg){
        const float4 w0 = *reinterpret_cast<const float4*>(r0 + kg*4);
        const float4 w1 = *reinterpret_cast<const float4*>(r1 + kg*4);
        const int k = 128 + half*128 + kg*4;
        #pragma unroll
        for (int bb = 0; bb < 4; ++bb){
          const float4 xv = *reinterpret_cast<const float4*>(&S[bb][k]);
          a0[bb] += w0.x*xv.x + w0.y*xv.y + w0.z*xv.z + w0.w*xv.w;
          a1[bb] += w1.x*xv.x + w1.y*xv.y + w1.z*xv.z + w1.w*xv.w;
        }
      }
      float* gp = half ? &gp1[0][0] : &gp0[0][0];
      #pragma unroll
      for (int bb = 0; bb < 4; ++bb){
        gp[bb*512 + j0]   = a0[bb];
        gp[bb*512 + j0+1] = a1[bb];
      }
    }
    __syncthreads();
    // --- A3: update h1, c1
    {
      const int bb = tid >> 7, u = tid & 127;
      const float gi = gp0[bb][u]     + gp1[bb][u]     + bs1[u];
      const float gf = gp0[bb][128+u] + gp1[bb][128+u] + bs1[128+u];
      const float gg = gp0[bb][256+u] + gp1[bb][256+u] + bs1[256+u];
      const float go = gp0[bb][384+u] + gp1[bb][384+u] + bs1[384+u];
      const float c = sigm(gf)*S[bb][384+u] + sigm(gi)*fast_tanh(gg);
      S[bb][384+u] = c;
      S[bb][256+u] = sigm(go)*fast_tanh(c);
    }
    __syncthreads();
  }
  // --- final projection
  {
    const int bb = wv & 3;
    float v = S[bb][256+l]*projWs[l] + S[bb][320+l]*projWs[64+l]
            + parts[bb][l]*projWs[128+l] + parts[bb][64+l]*projWs[192+l];
    v = wave_sum(v);
    if (l == 0) p.out[b0 + bb] = v + pb;
  }
}

extern "C" void kernel_launch(void* const* d_in, const int* in_sizes, int n_in,
                              void* d_out, int out_size, void* d_ws, size_t ws_size,
                              hipStream_t stream){
  Params p;
  p.input = (const float*)d_in[0];
  p.eWih0=(const float*)d_in[1];  p.eWhh0=(const float*)d_in[2];
  p.ebih0=(const float*)d_in[3];  p.ebhh0=(const float*)d_in[4];
  p.eWih1=(const float*)d_in[5];  p.eWhh1=(const float*)d_in[6];
  p.ebih1=(const float*)d_in[7];  p.ebhh1=(const float*)d_in[8];
  p.dWih0=(const float*)d_in[9];  p.dWhh0=(const float*)d_in[10];
  p.dbih0=(const float*)d_in[11]; p.dbhh0=(const float*)d_in[12];
  p.dWih1=(const float*)d_in[13]; p.dWhh1=(const float*)d_in[14];
  p.dbih1=(const float*)d_in[15]; p.dbhh1=(const float*)d_in[16];
  p.aW1=(const float*)d_in[17];   p.ab1=(const float*)d_in[18];
  p.aW2=(const float*)d_in[19];   p.ab2=(const float*)d_in[20];
  p.adW1=(const float*)d_in[21];  p.adb1=(const float*)d_in[22];
  p.adW2=(const float*)d_in[23];  p.adb2=(const float*)d_in[24];
  p.dinW=(const float*)d_in[25];  p.dinb=(const float*)d_in[26];
  p.projW=(const float*)d_in[27]; p.projb=(const float*)d_in[28];
  p.ws = (float*)d_ws;
  p.out = (float*)d_out;

  hipLaunchKernelGGL(k_prep,  dim3(128), dim3(256), 0, stream, p);
  hipLaunchKernelGGL(k_xproj, dim3(BATCH), dim3(256), 0, stream, p);
  hipLaunchKernelGGL(k_enc,   dim3(128), dim3(512), 0, stream, p);
  hipLaunchKernelGGL(k_hproj, dim3(BATCH), dim3(256), 0, stream, p);
  hipLaunchKernelGGL(k_dec,   dim3(128), dim3(512), 0, stream, p);
}